// Round 1
// baseline (273.136 us; speedup 1.0000x reference)
//
#include <hip/hip_runtime.h>
#include <stdint.h>

#define H_B  4
#define H_SQ 1024
#define H_SK 2048
#define H_D  1024
#define H_NH 16
#define H_DH 64

typedef __bf16 bf16x8 __attribute__((ext_vector_type(8)));
typedef float  f32x4  __attribute__((ext_vector_type(4)));

__device__ __forceinline__ uint16_t f2bf(float f) {
    union { float f; uint32_t u; } v; v.f = f;
    uint32_t r = v.u + 0x7fffu + ((v.u >> 16) & 1u);
    return (uint16_t)(r >> 16);
}

__device__ __forceinline__ void gload_lds16(const void* g, void* l) {
    __builtin_amdgcn_global_load_lds(
        (const __attribute__((address_space(1))) uint32_t*)g,
        (__attribute__((address_space(3))) uint32_t*)l, 16, 0, 0);
}

#define MFMA_BF16(a, b, c) __builtin_amdgcn_mfma_f32_16x16x32_bf16((a), (b), (c), 0, 0, 0)

// ---------------- f32 -> bf16 convert (vectorized, grid-stride) ----------------
__global__ void cvt_bf16_kernel(const float* __restrict__ in, uint16_t* __restrict__ out, int n4) {
    int i = blockIdx.x * blockDim.x + threadIdx.x;
    int stride = gridDim.x * blockDim.x;
    for (; i < n4; i += stride) {
        float4 v = ((const float4*)in)[i];
        ushort4 o;
        o.x = f2bf(v.x); o.y = f2bf(v.y); o.z = f2bf(v.z); o.w = f2bf(v.w);
        ((ushort4*)out)[i] = o;
    }
}

// ---------------- weight transpose + convert: W[K][N] f32 -> WT[N][K] bf16 ------
__global__ void wtrans_kernel(const float* __restrict__ W, uint16_t* __restrict__ WT, int K, int N) {
    __shared__ float tile[32][33];
    int n0 = blockIdx.x * 32, k0 = blockIdx.y * 32;
    int tx = threadIdx.x, ty = threadIdx.y;           // block (32,8)
    #pragma unroll
    for (int i = ty; i < 32; i += 8)
        tile[i][tx] = W[(size_t)(k0 + i) * N + n0 + tx];
    __syncthreads();
    #pragma unroll
    for (int i = ty; i < 32; i += 8)
        WT[(size_t)(n0 + i) * K + k0 + tx] = f2bf(tile[tx][i]);
}

// ---------------- v transpose: kv[B*Sk][2D] v-half -> vT[(b*16+h)*64+d][Sk] -----
__global__ __launch_bounds__(256) void vtrans_kernel(const uint16_t* __restrict__ kv,
                                                     uint16_t* __restrict__ vT) {
    __shared__ uint16_t tile[64][68];
    int bid = blockIdx.x;          // (b*16+h)*32 + sk-tile
    int st = bid & 31;
    int bh = bid >> 5;
    int b = bh >> 4, hh = bh & 15;
    int sk0 = st * 64;
    int t = threadIdx.x;
    for (int c = t; c < 512; c += 256) {
        int r = c >> 3, dp = c & 7;
        const uint16_t* g = kv + (size_t)(b * H_SK + sk0 + r) * (2 * H_D) + H_D + hh * H_DH + dp * 8;
        uint4 v = *(const uint4*)g;
        *(uint2*)&tile[r][dp * 8]     = make_uint2(v.x, v.y);
        *(uint2*)&tile[r][dp * 8 + 4] = make_uint2(v.z, v.w);
    }
    __syncthreads();
    for (int c = t; c < 512; c += 256) {
        int d = c >> 3, sp = c & 7;
        alignas(16) uint16_t tmp[8];
        #pragma unroll
        for (int i = 0; i < 8; ++i) tmp[i] = tile[sp * 8 + i][d];
        uint16_t* g = vT + ((size_t)(bh * H_DH + d)) * H_SK + sk0 + sp * 8;
        *(uint4*)g = *(const uint4*)tmp;
    }
}

// ---------------- GEMM: C[M][N] = A[M][K] @ BT[N][K]^T + bias, bf16 in ----------
template <typename OUT_T>
__global__ __launch_bounds__(256) void gemm_bt_kernel(
    const uint16_t* __restrict__ A, const uint16_t* __restrict__ BT,
    const float* __restrict__ bias, OUT_T* __restrict__ C,
    int M, int N, int K)
{
    __shared__ uint16_t As[128 * 32];
    __shared__ uint16_t Bs[128 * 32];

    int nbn = N >> 7;
    int nwg = gridDim.x;
    int cpx = nwg >> 3;                         // nwg divisible by 8 for all our shapes
    int wg = blockIdx.x;
    wg = (wg & 7) * cpx + (wg >> 3);            // XCD-aware swizzle (bijective)
    int bm = wg / nbn, bn = wg % nbn;

    int t = threadIdx.x;
    int w = t >> 6, l = t & 63;
    int lr = l & 15, lg = l >> 4;
    int wr = (w >> 1) * 64, wc = (w & 1) * 64;

    const uint16_t* Ab = A + (size_t)bm * 128 * K;
    const uint16_t* Bb = BT + (size_t)bn * 128 * K;

    f32x4 acc[4][4];
    #pragma unroll
    for (int i = 0; i < 4; ++i)
        #pragma unroll
        for (int j = 0; j < 4; ++j) acc[i][j] = {0.f, 0.f, 0.f, 0.f};

    for (int k0 = 0; k0 < K; k0 += 32) {
        __syncthreads();
        #pragma unroll
        for (int i = 0; i < 2; ++i) {
            int c = i * 256 + w * 64 + l;
            int row = c >> 2, kp = c & 3;
            gload_lds16(Ab + (size_t)row * K + k0 + kp * 8, (char*)As + (i * 256 + w * 64) * 16);
            gload_lds16(Bb + (size_t)row * K + k0 + kp * 8, (char*)Bs + (i * 256 + w * 64) * 16);
        }
        __syncthreads();
        bf16x8 af[4], bf[4];
        #pragma unroll
        for (int mi = 0; mi < 4; ++mi)
            af[mi] = *(const bf16x8*)&As[(wr + mi * 16 + lr) * 32 + lg * 8];
        #pragma unroll
        for (int ni = 0; ni < 4; ++ni)
            bf[ni] = *(const bf16x8*)&Bs[(wc + ni * 16 + lr) * 32 + lg * 8];
        #pragma unroll
        for (int mi = 0; mi < 4; ++mi)
            #pragma unroll
            for (int ni = 0; ni < 4; ++ni)
                acc[mi][ni] = MFMA_BF16(af[mi], bf[ni], acc[mi][ni]);
    }

    #pragma unroll
    for (int mi = 0; mi < 4; ++mi) {
        #pragma unroll
        for (int ni = 0; ni < 4; ++ni) {
            int col = bn * 128 + wc + ni * 16 + lr;
            float bv = bias[col];
            #pragma unroll
            for (int j = 0; j < 4; ++j) {
                int row = bm * 128 + wr + mi * 16 + lg * 4 + j;
                float v = acc[mi][ni][j] + bv;
                if constexpr (sizeof(OUT_T) == 2) C[(size_t)row * N + col] = f2bf(v);
                else                              C[(size_t)row * N + col] = v;
            }
        }
    }
}

// ---------------- flash attention ------------------------------------------------
// grid: (b*16+h)*16 + qt ; 256 threads = 4 waves, each wave owns 16 q-rows
__global__ __launch_bounds__(256) void attn_kernel(
    const uint16_t* __restrict__ qb, const uint16_t* __restrict__ kvb,
    const uint16_t* __restrict__ vT, const float* __restrict__ mask,
    uint16_t* __restrict__ ab)
{
    __shared__ uint16_t q_lds[64][72];
    __shared__ uint16_t k_lds[64][72];
    __shared__ uint16_t vt_lds[64][72];
    __shared__ uint16_t p_lds[4][16][72];
    __shared__ float mask_lds[64];

    int bid = blockIdx.x;
    int qt = bid & 15;
    int bh = bid >> 4;
    int b = bh >> 4, hh = bh & 15;

    int t = threadIdx.x;
    int w = t >> 6, l = t & 63;
    int lr = l & 15, lg = l >> 4;

    // stage Q once
    for (int c = t; c < 512; c += 256) {
        int r = c >> 3, dp = c & 7;
        const uint16_t* g = qb + (size_t)(b * H_SQ + qt * 64 + r) * H_D + hh * H_DH + dp * 8;
        *(uint4*)&q_lds[r][dp * 8] = *(const uint4*)g;
    }
    __syncthreads();

    bf16x8 qf0 = *(const bf16x8*)&q_lds[w * 16 + lr][lg * 8];
    bf16x8 qf1 = *(const bf16x8*)&q_lds[w * 16 + lr][32 + lg * 8];

    f32x4 acc[4];
    #pragma unroll
    for (int i = 0; i < 4; ++i) acc[i] = {0.f, 0.f, 0.f, 0.f};
    float mrow[4], lsum[4];
    #pragma unroll
    for (int j = 0; j < 4; ++j) { mrow[j] = -1e30f; lsum[j] = 0.f; }

    const float SC  = 0.18033688011112042f;   // log2(e)/8
    const float L2E = 1.4426950408889634f;

    for (int kt = 0; kt < H_SK / 64; ++kt) {
        __syncthreads();
        int sk0 = kt * 64;
        for (int c = t; c < 512; c += 256) {
            int r = c >> 3, dp = c & 7;
            const uint16_t* gk = kvb + (size_t)(b * H_SK + sk0 + r) * (2 * H_D) + hh * H_DH + dp * 8;
            *(uint4*)&k_lds[r][dp * 8] = *(const uint4*)gk;
            const uint16_t* gv = vT + (size_t)(bh * H_DH + r) * H_SK + sk0 + dp * 8;
            *(uint4*)&vt_lds[r][dp * 8] = *(const uint4*)gv;
        }
        if (t < 64) mask_lds[t] = mask[b * H_SK + sk0 + t];
        __syncthreads();

        // S = Q K^T
        f32x4 s[4];
        #pragma unroll
        for (int ni = 0; ni < 4; ++ni) s[ni] = {0.f, 0.f, 0.f, 0.f};
        #pragma unroll
        for (int ni = 0; ni < 4; ++ni) {
            bf16x8 kf0 = *(const bf16x8*)&k_lds[ni * 16 + lr][lg * 8];
            bf16x8 kf1 = *(const bf16x8*)&k_lds[ni * 16 + lr][32 + lg * 8];
            s[ni] = MFMA_BF16(qf0, kf0, s[ni]);
            s[ni] = MFMA_BF16(qf1, kf1, s[ni]);
        }

        // online softmax in exp2 domain
        float mv[4];
        #pragma unroll
        for (int ni = 0; ni < 4; ++ni) mv[ni] = mask_lds[ni * 16 + lr] * L2E;
        float lg2[4][4], mx[4];
        #pragma unroll
        for (int j = 0; j < 4; ++j) {
            float a0 = s[0][j] * SC + mv[0];
            float a1 = s[1][j] * SC + mv[1];
            float a2 = s[2][j] * SC + mv[2];
            float a3 = s[3][j] * SC + mv[3];
            lg2[0][j] = a0; lg2[1][j] = a1; lg2[2][j] = a2; lg2[3][j] = a3;
            mx[j] = fmaxf(fmaxf(a0, a1), fmaxf(a2, a3));
        }
        #pragma unroll
        for (int off = 8; off >= 1; off >>= 1)
            #pragma unroll
            for (int j = 0; j < 4; ++j)
                mx[j] = fmaxf(mx[j], __shfl_xor(mx[j], off, 16));
        float alpha[4];
        #pragma unroll
        for (int j = 0; j < 4; ++j) {
            float mn = fmaxf(mrow[j], mx[j]);
            alpha[j] = exp2f(mrow[j] - mn);
            mrow[j] = mn;
        }
        float rs[4] = {0.f, 0.f, 0.f, 0.f};
        #pragma unroll
        for (int ni = 0; ni < 4; ++ni)
            #pragma unroll
            for (int j = 0; j < 4; ++j) {
                float p = exp2f(lg2[ni][j] - mrow[j]);
                rs[j] += p;
                p_lds[w][lg * 4 + j][ni * 16 + lr] = f2bf(p);
            }
        #pragma unroll
        for (int off = 8; off >= 1; off >>= 1)
            #pragma unroll
            for (int j = 0; j < 4; ++j)
                rs[j] += __shfl_xor(rs[j], off, 16);
        #pragma unroll
        for (int j = 0; j < 4; ++j) lsum[j] = lsum[j] * alpha[j] + rs[j];
        #pragma unroll
        for (int ni = 0; ni < 4; ++ni)
            #pragma unroll
            for (int j = 0; j < 4; ++j) acc[ni][j] *= alpha[j];

        // O += P V  (p_lds is wave-private; compiler inserts lgkm waits)
        bf16x8 pf0 = *(const bf16x8*)&p_lds[w][lr][lg * 8];
        bf16x8 pf1 = *(const bf16x8*)&p_lds[w][lr][32 + lg * 8];
        #pragma unroll
        for (int ni = 0; ni < 4; ++ni) {
            bf16x8 vf0 = *(const bf16x8*)&vt_lds[ni * 16 + lr][lg * 8];
            bf16x8 vf1 = *(const bf16x8*)&vt_lds[ni * 16 + lr][32 + lg * 8];
            acc[ni] = MFMA_BF16(pf0, vf0, acc[ni]);
            acc[ni] = MFMA_BF16(pf1, vf1, acc[ni]);
        }
    }

    float inv[4];
    #pragma unroll
    for (int j = 0; j < 4; ++j) inv[j] = 1.0f / lsum[j];
    #pragma unroll
    for (int ni = 0; ni < 4; ++ni)
        #pragma unroll
        for (int j = 0; j < 4; ++j) {
            int row = qt * 64 + w * 16 + lg * 4 + j;
            int col = hh * H_DH + ni * 16 + lr;
            ab[(size_t)(b * H_SQ + row) * H_D + col] = f2bf(acc[ni][j] * inv[j]);
        }
}

// ---------------- host ----------------------------------------------------------
extern "C" void kernel_launch(void* const* d_in, const int* in_sizes, int n_in,
                              void* d_out, int out_size, void* d_ws, size_t ws_size,
                              hipStream_t stream) {
    const float* x    = (const float*)d_in[0];
    const float* ctx  = (const float*)d_in[1];
    const float* mask = (const float*)d_in[2];
    const float* Wq   = (const float*)d_in[3];
    const float* bq   = (const float*)d_in[4];
    const float* Wkv  = (const float*)d_in[5];
    const float* bkv  = (const float*)d_in[6];
    const float* Wp   = (const float*)d_in[7];
    const float* bp   = (const float*)d_in[8];
    float* out = (float*)d_out;

    char* ws = (char*)d_ws;
    uint16_t* xb   = (uint16_t*)(ws + 0);          // 8MB   (reused as ab)
    uint16_t* ctxb = (uint16_t*)(ws + 8388608);    // 16MB  (reused as vT)
    uint16_t* WqT  = (uint16_t*)(ws + 25165824);   // 2MB
    uint16_t* WkvT = (uint16_t*)(ws + 27262976);   // 4MB
    uint16_t* WpT  = (uint16_t*)(ws + 31457280);   // 2MB
    uint16_t* qb   = (uint16_t*)(ws + 33554432);   // 8MB
    uint16_t* kvb  = (uint16_t*)(ws + 41943040);   // 32MB -> total 72MB
    uint16_t* vTb  = ctxb;                          // alias: ctxb dead after kv GEMM
    uint16_t* ab   = xb;                            // alias: xb dead after q GEMM

    cvt_bf16_kernel<<<2048, 256, 0, stream>>>(x,   xb,   (H_B * H_SQ * H_D) / 4);
    cvt_bf16_kernel<<<2048, 256, 0, stream>>>(ctx, ctxb, (H_B * H_SK * H_D) / 4);

    wtrans_kernel<<<dim3(32, 32), dim3(32, 8), 0, stream>>>(Wq,  WqT,  H_D, H_D);
    wtrans_kernel<<<dim3(64, 32), dim3(32, 8), 0, stream>>>(Wkv, WkvT, H_D, 2 * H_D);
    wtrans_kernel<<<dim3(32, 32), dim3(32, 8), 0, stream>>>(Wp,  WpT,  H_D, H_D);

    gemm_bt_kernel<uint16_t><<<256, 256, 0, stream>>>(xb,   WqT,  bq,  qb,  H_B * H_SQ, H_D,     H_D);
    gemm_bt_kernel<uint16_t><<<1024, 256, 0, stream>>>(ctxb, WkvT, bkv, kvb, H_B * H_SK, 2 * H_D, H_D);

    vtrans_kernel<<<H_B * H_NH * (H_SK / 64), 256, 0, stream>>>(kvb, vTb);

    attn_kernel<<<H_B * H_NH * (H_SQ / 64), 256, 0, stream>>>(qb, kvb, vTb, mask, ab);

    gemm_bt_kernel<float><<<256, 256, 0, stream>>>(ab, WpT, bp, out, H_B * H_SQ, H_D, H_D);
}